// Round 1
// baseline (386.092 us; speedup 1.0000x reference)
//
#include <hip/hip_runtime.h>
#include <math.h>

#define BB   2
#define DD   192
#define LL   4096
#define KK   8
#define NN   16
#define RR   6
#define C38  38
#define CPAD 40
#define NCH  32
#define CLEN 128   // NCH * CLEN == LL

// xs[b,k,d,l] = x[b,d,src_index(k,l)]  (plane offset within H*W)
__device__ __forceinline__ int src_index(int k, int l) {
  int ll = (k & 2) ? (LL - 1 - l) : l;   // k in {2,3,6,7} are reversed
  int kb = k & 5;                         // 0,1,4,5
  if (kb == 0) return ll;
  int h = ll & 63, w = ll >> 6;
  if (kb == 1) return (h << 6) + w;
  if (kb == 4) return (h << 6) + ((h + w) & 63);
  return (h << 6) + ((w - h) & 63);       // kb == 5
}

// x (b,d,l) -> xT (b,l,d)
__global__ __launch_bounds__(256) void transpose_x(const float* __restrict__ x,
                                                   float* __restrict__ xT) {
  __shared__ float tile[32][33];
  int b  = blockIdx.z;
  int p0 = blockIdx.x * 32;
  int d0 = blockIdx.y * 32;
  int tx = threadIdx.x, ty = threadIdx.y;  // 32 x 8
  #pragma unroll
  for (int i = 0; i < 32; i += 8)
    tile[ty + i][tx] = x[((size_t)(b * DD + d0 + ty + i)) * LL + p0 + tx];
  __syncthreads();
  #pragma unroll
  for (int i = 0; i < 32; i += 8)
    xT[((size_t)(b * LL + p0 + ty + i)) * DD + d0 + tx] = tile[tx][ty + i];
}

// x_dbl[b,k,l,c] = sum_d xT[b, src_k(l), d] * W[k,c,d];  c<38, row padded to 40
__global__ __launch_bounds__(256) void proj_kernel(const float* __restrict__ xT,
                                                   const float* __restrict__ W,
                                                   float* __restrict__ xdbl) {
  int k = blockIdx.y, b = blockIdx.z;
  int l = blockIdx.x * 256 + threadIdx.x;
  __shared__ __align__(16) float Wt[DD][CPAD];  // 30720 B
  for (int i = threadIdx.x; i < C38 * DD; i += 256) {
    int c = i / DD, d = i - c * DD;
    Wt[d][c] = W[(k * C38 + c) * DD + d];
  }
  for (int d = threadIdx.x; d < DD; d += 256) { Wt[d][38] = 0.f; Wt[d][39] = 0.f; }
  __syncthreads();

  int p = src_index(k, l);
  const float4* xrow4 = (const float4*)(xT + (size_t)(b * LL + p) * DD);
  float4 acc[10];
  #pragma unroll
  for (int c = 0; c < 10; ++c) acc[c] = make_float4(0.f, 0.f, 0.f, 0.f);

  for (int d4 = 0; d4 < DD / 4; ++d4) {
    float4 xv = xrow4[d4];
    #pragma unroll
    for (int s = 0; s < 4; ++s) {
      float xs = (s == 0) ? xv.x : (s == 1) ? xv.y : (s == 2) ? xv.z : xv.w;
      const float4* w4 = (const float4*)Wt[d4 * 4 + s];
      #pragma unroll
      for (int c = 0; c < 10; ++c) {
        float4 wv = w4[c];
        acc[c].x = fmaf(wv.x, xs, acc[c].x);
        acc[c].y = fmaf(wv.y, xs, acc[c].y);
        acc[c].z = fmaf(wv.z, xs, acc[c].z);
        acc[c].w = fmaf(wv.w, xs, acc[c].w);
      }
    }
  }
  float* orow = xdbl + ((size_t)((b * KK + k) * LL) + l) * CPAD;
  float4* o4 = (float4*)orow;
  #pragma unroll
  for (int c = 0; c < 9; ++c) o4[c] = acc[c];
  orow[36] = acc[9].x;
  orow[37] = acc[9].y;
}

__device__ __forceinline__ float softplus_f(float x) {
  return fmaxf(x, 0.f) + log1pf(__expf(-fabsf(x)));
}

// Phase A (FINAL=false): per-chunk P = prod(exp(delta*A)), q = local final h  (h0 = 0)
// Phase C (FINAL=true):  full recurrence from stitched h0, emits y, scatter-adds merged output
template <bool FINAL>
__global__ __launch_bounds__(64) void scan_kernel(
    const float* __restrict__ xT, const float* __restrict__ xdbl,
    const float* __restrict__ A_logs, const float* __restrict__ dtw,
    const float* __restrict__ dtb, const float* __restrict__ Ds,
    const float* __restrict__ H0, float* __restrict__ Pq, float* __restrict__ Y) {
  int lane = threadIdx.x;
  int bk = blockIdx.x;            // 0..15
  int b = bk >> 3, k = bk & 7;
  int dg = blockIdx.y;            // 0..2
  int chunk = blockIdx.z;         // 0..NCH-1
  int d = dg * 64 + lane;
  int kd = k * DD + d;
  int ch = bk * DD + d;           // channel id 0..3071

  float An[NN];
  #pragma unroll
  for (int n = 0; n < NN; ++n) An[n] = -__expf(A_logs[kd * NN + n]);
  float wdt[RR];
  #pragma unroll
  for (int r = 0; r < RR; ++r) wdt[r] = dtw[kd * RR + r];
  float bias = dtb[kd];
  float dval = FINAL ? Ds[kd] : 0.f;

  float h[NN], P[NN];
  #pragma unroll
  for (int n = 0; n < NN; ++n) { h[n] = 0.f; P[n] = 1.f; }
  if (FINAL) {
    const float* h0p = H0 + ((size_t)ch * NCH + chunk) * NN;
    #pragma unroll
    for (int n = 0; n < NN; ++n) h[n] = h0p[n];
  }

  int l0 = chunk * CLEN;
  const float* row = xdbl + ((size_t)(bk * LL) + l0) * CPAD;  // wave-uniform
  for (int t = 0; t < CLEN; ++t, row += CPAD) {
    int l = l0 + t;
    int p = src_index(k, l);
    float u = xT[(size_t)(b * LL + p) * DD + d];
    float dts = bias;
    #pragma unroll
    for (int r = 0; r < RR; ++r) dts = fmaf(row[r], wdt[r], dts);
    float sp = softplus_f(dts);
    float du = sp * u;
    float y = 0.f;
    #pragma unroll
    for (int n = 0; n < NN; ++n) {
      float e = __expf(sp * An[n]);
      h[n] = fmaf(h[n], e, du * row[6 + n]);
      if (FINAL) y = fmaf(h[n], row[22 + n], y);
      else       P[n] *= e;
    }
    if (FINAL) {
      float outv = fmaf(u, dval, y);           // ys + u*Ds
      atomicAdd(&Y[(size_t)(b * LL + p) * DD + d], outv);  // fused cross_merge
    }
  }
  if (!FINAL) {
    float* o = Pq + ((size_t)ch * NCH + chunk) * (2 * NN);
    #pragma unroll
    for (int n = 0; n < NN; ++n) { o[n] = P[n]; o[NN + n] = h[n]; }
  }
}

// exclusive scan over chunks: H0[ch,c,n] = h before chunk c
__global__ __launch_bounds__(256) void stitch_kernel(const float* __restrict__ Pq,
                                                     float* __restrict__ H0) {
  int t = blockIdx.x * 256 + threadIdx.x;  // 0..49151
  int ch = t >> 4, n = t & 15;
  float h = 0.f;
  for (int c = 0; c < NCH; ++c) {
    H0[((size_t)ch * NCH + c) * NN + n] = h;
    const float* pq = Pq + ((size_t)ch * NCH + c) * (2 * NN);
    h = fmaf(pq[n], h, pq[NN + n]);
  }
}

// LayerNorm over D per (b,l); Y is (b,l,d), out is (b,h,w,d) = same layout
__global__ __launch_bounds__(256) void ln_kernel(const float* __restrict__ Y,
                                                 const float* __restrict__ lw,
                                                 const float* __restrict__ lb,
                                                 float* __restrict__ out) {
  int lane = threadIdx.x & 63;
  int row = blockIdx.x * 4 + (threadIdx.x >> 6);
  const float* yr = Y + (size_t)row * DD;
  float v0 = yr[lane], v1 = yr[lane + 64], v2 = yr[lane + 128];
  float s1 = v0 + v1 + v2;
  float s2 = v0 * v0 + v1 * v1 + v2 * v2;
  #pragma unroll
  for (int m = 32; m >= 1; m >>= 1) {
    s1 += __shfl_xor(s1, m, 64);
    s2 += __shfl_xor(s2, m, 64);
  }
  float mu = s1 * (1.f / DD);
  float var = s2 * (1.f / DD) - mu * mu;
  float inv = rsqrtf(var + 1e-5f);
  float* orow = out + (size_t)row * DD;
  orow[lane]       = (v0 - mu) * inv * lw[lane]       + lb[lane];
  orow[lane + 64]  = (v1 - mu) * inv * lw[lane + 64]  + lb[lane + 64];
  orow[lane + 128] = (v2 - mu) * inv * lw[lane + 128] + lb[lane + 128];
}

extern "C" void kernel_launch(void* const* d_in, const int* in_sizes, int n_in,
                              void* d_out, int out_size, void* d_ws, size_t ws_size,
                              hipStream_t stream) {
  const float* x      = (const float*)d_in[0];
  const float* xpw    = (const float*)d_in[1];
  const float* dtw    = (const float*)d_in[2];
  const float* dtb    = (const float*)d_in[3];
  const float* A_logs = (const float*)d_in[4];
  const float* Ds     = (const float*)d_in[5];
  const float* ln_w   = (const float*)d_in[6];
  const float* ln_b   = (const float*)d_in[7];
  float* out = (float*)d_out;

  float* ws   = (float*)d_ws;
  float* xT   = ws;                    // B*L*D       = 1572864
  float* xdbl = xT + 1572864;          // B*K*L*CPAD  = 2621440
  float* Pq   = xdbl + 2621440;        // 3072*32*32  = 3145728
  float* H0   = Pq + 3145728;          // 3072*32*16  = 1572864
  float* Y    = H0 + 1572864;          // B*L*D       = 1572864

  hipMemsetAsync(Y, 0, 1572864 * sizeof(float), stream);
  transpose_x<<<dim3(LL / 32, DD / 32, BB), dim3(32, 8), 0, stream>>>(x, xT);
  proj_kernel<<<dim3(LL / 256, KK, BB), 256, 0, stream>>>(xT, xpw, xdbl);
  scan_kernel<false><<<dim3(BB * KK, DD / 64, NCH), 64, 0, stream>>>(
      xT, xdbl, A_logs, dtw, dtb, Ds, nullptr, Pq, nullptr);
  stitch_kernel<<<(3072 * NN) / 256, 256, 0, stream>>>(Pq, H0);
  scan_kernel<true><<<dim3(BB * KK, DD / 64, NCH), 64, 0, stream>>>(
      xT, xdbl, A_logs, dtw, dtb, Ds, H0, nullptr, Y);
  ln_kernel<<<(BB * LL) / 4, 256, 0, stream>>>(Y, ln_w, ln_b, out);
}

// Round 2
// 285.186 us; speedup vs baseline: 1.3538x; 1.3538x over previous
//
#include <hip/hip_runtime.h>
#include <math.h>

#define BB   2
#define DD   192
#define LL   4096
#define KK   8
#define NN   16
#define RR   6
#define C38  38
#define CPAD 40
#define PQS  17   // per-chunk record: [S, q0..q15]; q overwritten with h0 by stitch

__device__ __forceinline__ float fexp2(float x) { return __builtin_amdgcn_exp2f(x); }
__device__ __forceinline__ float flog2(float x) { return __builtin_amdgcn_logf(x); }

// softplus(x) = log(1+e^x), fast path (abs err ~1e-6, threshold is 0.138)
__device__ __forceinline__ float softplus_f(float x) {
  return fmaxf(x, 0.f) + 0.69314718f * flog2(1.f + fexp2(-1.44269504f * fabsf(x)));
}

// xs[b,k,d,l] = x[b,d,src_index(k,l)]
__device__ __forceinline__ int src_index(int k, int l) {
  int ll = (k & 2) ? (LL - 1 - l) : l;
  int kb = k & 5;
  if (kb == 0) return ll;
  int h = ll & 63, w = ll >> 6;
  if (kb == 1) return (h << 6) + w;
  if (kb == 4) return (h << 6) + ((h + w) & 63);
  return (h << 6) + ((w - h) & 63);
}

__global__ __launch_bounds__(256) void transpose_x(const float* __restrict__ x,
                                                   float* __restrict__ xT) {
  __shared__ float tile[32][33];
  int b  = blockIdx.z;
  int p0 = blockIdx.x * 32;
  int d0 = blockIdx.y * 32;
  int tx = threadIdx.x, ty = threadIdx.y;
  #pragma unroll
  for (int i = 0; i < 32; i += 8)
    tile[ty + i][tx] = x[((size_t)(b * DD + d0 + ty + i)) * LL + p0 + tx];
  __syncthreads();
  #pragma unroll
  for (int i = 0; i < 32; i += 8)
    xT[((size_t)(b * LL + p0 + ty + i)) * DD + d0 + tx] = tile[tx][ty + i];
}

__global__ __launch_bounds__(256) void proj_kernel(const float* __restrict__ xT,
                                                   const float* __restrict__ W,
                                                   float* __restrict__ xdbl) {
  int k = blockIdx.y, b = blockIdx.z;
  int l = blockIdx.x * 256 + threadIdx.x;
  __shared__ __align__(16) float Wt[DD][CPAD];
  for (int i = threadIdx.x; i < C38 * DD; i += 256) {
    int c = i / DD, d = i - c * DD;
    Wt[d][c] = W[(k * C38 + c) * DD + d];
  }
  for (int d = threadIdx.x; d < DD; d += 256) { Wt[d][38] = 0.f; Wt[d][39] = 0.f; }
  __syncthreads();

  int p = src_index(k, l);
  const float4* xrow4 = (const float4*)(xT + (size_t)(b * LL + p) * DD);
  float4 acc[10];
  #pragma unroll
  for (int c = 0; c < 10; ++c) acc[c] = make_float4(0.f, 0.f, 0.f, 0.f);

  for (int d4 = 0; d4 < DD / 4; ++d4) {
    float4 xv = xrow4[d4];
    #pragma unroll
    for (int s = 0; s < 4; ++s) {
      float xs = (s == 0) ? xv.x : (s == 1) ? xv.y : (s == 2) ? xv.z : xv.w;
      const float4* w4 = (const float4*)Wt[d4 * 4 + s];
      #pragma unroll
      for (int c = 0; c < 10; ++c) {
        float4 wv = w4[c];
        acc[c].x = fmaf(wv.x, xs, acc[c].x);
        acc[c].y = fmaf(wv.y, xs, acc[c].y);
        acc[c].z = fmaf(wv.z, xs, acc[c].z);
        acc[c].w = fmaf(wv.w, xs, acc[c].w);
      }
    }
  }
  float* orow = xdbl + ((size_t)((b * KK + k) * LL) + l) * CPAD;
  float4* o4 = (float4*)orow;
  #pragma unroll
  for (int c = 0; c < 9; ++c) o4[c] = acc[c];
  orow[36] = acc[9].x;
  orow[37] = acc[9].y;
}

// Phase A (FINAL=false): per chunk, S = sum(softplus) and q = local final h (h0=0).
// Phase C (FINAL=true): recurrence from stitched h0; scatter-adds merged output.
template <int NCH, bool FINAL>
__global__ __launch_bounds__(256, 4) void scan_kernel(
    const float* __restrict__ xT, const float* __restrict__ xdbl,
    const float* __restrict__ A_logs, const float* __restrict__ dtw,
    const float* __restrict__ dtb, const float* __restrict__ Ds,
    float* __restrict__ Pq, float* __restrict__ Y) {
  constexpr int CLEN = LL / NCH;
  int lane  = threadIdx.x;            // 0..63
  int bk    = blockIdx.x;             // 0..15
  int b = bk >> 3, k = bk & 7;
  int dg    = blockIdx.y;             // 0..2
  int chunk = blockIdx.z * 4 + threadIdx.y;
  int d  = dg * 64 + lane;
  int kd = k * DD + d;
  int ch = bk * DD + d;

  float An2[NN];
  #pragma unroll
  for (int n = 0; n < NN; ++n)
    An2[n] = -__expf(A_logs[kd * NN + n]) * 1.44269504f;  // pre-scale for exp2
  float wdt[RR];
  #pragma unroll
  for (int r = 0; r < RR; ++r) wdt[r] = dtw[kd * RR + r];
  float bias = dtb[kd];
  float dval = FINAL ? Ds[kd] : 0.f;

  float h[NN];
  float S = 0.f;
  if (FINAL) {
    const float* h0p = Pq + ((size_t)ch * NCH + chunk) * PQS + 1;
    #pragma unroll
    for (int n = 0; n < NN; ++n) h[n] = h0p[n];
  } else {
    #pragma unroll
    for (int n = 0; n < NN; ++n) h[n] = 0.f;
  }

  int l0 = chunk * CLEN;
  const float4* row4 = (const float4*)(xdbl + ((size_t)(bk * LL) + l0) * CPAD);
  for (int t = 0; t < CLEN; ++t, row4 += CPAD / 4) {
    int l = l0 + t;
    int p = src_index(k, l);
    float u = xT[(size_t)(b * LL + p) * DD + d];
    float rbuf[40];
    #pragma unroll
    for (int i = 0; i < (FINAL ? 10 : 6); ++i) ((float4*)rbuf)[i] = row4[i];
    float dts = bias;
    #pragma unroll
    for (int r = 0; r < RR; ++r) dts = fmaf(rbuf[r], wdt[r], dts);
    float sp = softplus_f(dts);
    float du = sp * u;
    float y = 0.f;
    #pragma unroll
    for (int n = 0; n < NN; ++n) {
      float e = fexp2(sp * An2[n]);
      h[n] = fmaf(h[n], e, du * rbuf[6 + n]);
      if (FINAL) y = fmaf(h[n], rbuf[22 + n], y);
    }
    if (FINAL) {
      float outv = fmaf(u, dval, y);
      atomicAdd(&Y[(size_t)(b * LL + p) * DD + d], outv);  // fused cross_merge
    } else {
      S += sp;
    }
  }
  if (!FINAL) {
    float* o = Pq + ((size_t)ch * NCH + chunk) * PQS;
    o[0] = S;
    #pragma unroll
    for (int n = 0; n < NN; ++n) o[1 + n] = h[n];
  }
}

// Exclusive scan over chunks; overwrites q slot with h0 (state before chunk).
__global__ __launch_bounds__(256) void stitch_kernel(float* __restrict__ Pq,
                                                     const float* __restrict__ A_logs,
                                                     int nch) {
  int t = blockIdx.x * 256 + threadIdx.x;  // 0..49151
  int ch = t >> 4, n = t & 15;
  int kd = ch & 1535;                      // ch % (K*D)
  float An2 = -__expf(A_logs[kd * NN + n]) * 1.44269504f;
  float h = 0.f;
  for (int c = 0; c < nch; ++c) {
    float* rec = Pq + ((size_t)ch * nch + c) * PQS;
    float S = rec[0];
    float q = rec[1 + n];
    rec[1 + n] = h;                        // h0 for chunk c
    h = fmaf(fexp2(An2 * S), h, q);
  }
}

__global__ __launch_bounds__(256) void ln_kernel(const float* __restrict__ Y,
                                                 const float* __restrict__ lw,
                                                 const float* __restrict__ lb,
                                                 float* __restrict__ out) {
  int lane = threadIdx.x & 63;
  int row = blockIdx.x * 4 + (threadIdx.x >> 6);
  const float* yr = Y + (size_t)row * DD;
  float v0 = yr[lane], v1 = yr[lane + 64], v2 = yr[lane + 128];
  float s1 = v0 + v1 + v2;
  float s2 = v0 * v0 + v1 * v1 + v2 * v2;
  #pragma unroll
  for (int m = 32; m >= 1; m >>= 1) {
    s1 += __shfl_xor(s1, m, 64);
    s2 += __shfl_xor(s2, m, 64);
  }
  float mu = s1 * (1.f / DD);
  float var = s2 * (1.f / DD) - mu * mu;
  float inv = rsqrtf(var + 1e-5f);
  float* orow = out + (size_t)row * DD;
  orow[lane]       = (v0 - mu) * inv * lw[lane]       + lb[lane];
  orow[lane + 64]  = (v1 - mu) * inv * lw[lane + 64]  + lb[lane + 64];
  orow[lane + 128] = (v2 - mu) * inv * lw[lane + 128] + lb[lane + 128];
}

extern "C" void kernel_launch(void* const* d_in, const int* in_sizes, int n_in,
                              void* d_out, int out_size, void* d_ws, size_t ws_size,
                              hipStream_t stream) {
  const float* x      = (const float*)d_in[0];
  const float* xpw    = (const float*)d_in[1];
  const float* dtw    = (const float*)d_in[2];
  const float* dtb    = (const float*)d_in[3];
  const float* A_logs = (const float*)d_in[4];
  const float* Ds     = (const float*)d_in[5];
  const float* ln_w   = (const float*)d_in[6];
  const float* ln_b   = (const float*)d_in[7];
  float* out = (float*)d_out;

  float* ws   = (float*)d_ws;
  float* xT   = ws;                    // B*L*D       = 1572864 floats
  float* xdbl = xT + 1572864;          // B*K*L*CPAD  = 2621440
  float* Y    = xdbl + 2621440;        // B*L*D       = 1572864
  float* Pq   = Y + 1572864;           // 3072*nch*17 floats

  size_t base_f = 1572864 + 2621440 + 1572864;
  auto need = [&](int nch) { return (base_f + (size_t)3072 * nch * PQS) * sizeof(float); };
  int nch = 128;
  if (need(128) > ws_size) nch = 64;
  if (need(64) > ws_size) nch = 32;

  hipMemsetAsync(Y, 0, 1572864 * sizeof(float), stream);
  transpose_x<<<dim3(LL / 32, DD / 32, BB), dim3(32, 8), 0, stream>>>(x, xT);
  proj_kernel<<<dim3(LL / 256, KK, BB), 256, 0, stream>>>(xT, xpw, xdbl);

  dim3 sblk(64, 4, 1);
  switch (nch) {
    case 128: {
      dim3 sg(BB * KK, 3, 128 / 4);
      scan_kernel<128, false><<<sg, sblk, 0, stream>>>(xT, xdbl, A_logs, dtw, dtb, Ds, Pq, Y);
      stitch_kernel<<<192, 256, 0, stream>>>(Pq, A_logs, 128);
      scan_kernel<128, true><<<sg, sblk, 0, stream>>>(xT, xdbl, A_logs, dtw, dtb, Ds, Pq, Y);
      break;
    }
    case 64: {
      dim3 sg(BB * KK, 3, 64 / 4);
      scan_kernel<64, false><<<sg, sblk, 0, stream>>>(xT, xdbl, A_logs, dtw, dtb, Ds, Pq, Y);
      stitch_kernel<<<192, 256, 0, stream>>>(Pq, A_logs, 64);
      scan_kernel<64, true><<<sg, sblk, 0, stream>>>(xT, xdbl, A_logs, dtw, dtb, Ds, Pq, Y);
      break;
    }
    default: {
      dim3 sg(BB * KK, 3, 32 / 4);
      scan_kernel<32, false><<<sg, sblk, 0, stream>>>(xT, xdbl, A_logs, dtw, dtb, Ds, Pq, Y);
      stitch_kernel<<<192, 256, 0, stream>>>(Pq, A_logs, 32);
      scan_kernel<32, true><<<sg, sblk, 0, stream>>>(xT, xdbl, A_logs, dtw, dtb, Ds, Pq, Y);
      break;
    }
  }
  ln_kernel<<<(BB * LL) / 4, 256, 0, stream>>>(Y, ln_w, ln_b, out);
}

// Round 3
// 252.675 us; speedup vs baseline: 1.5280x; 1.1287x over previous
//
#include <hip/hip_runtime.h>
#include <math.h>

#define BB   2
#define DD   192
#define LL   4096
#define KK   8
#define NN   16
#define RR   6
#define C38  38
#define CPAD 40
#define PQS  17   // per-chunk record: [S, q0..q15]; q overwritten with h0 by stitch
#define NCH  64   // chunks per channel
#define CLEN (LL / NCH)

__device__ __forceinline__ float fexp2(float x) { return __builtin_amdgcn_exp2f(x); }
__device__ __forceinline__ float flog2(float x) { return __builtin_amdgcn_logf(x); }

__device__ __forceinline__ float softplus_f(float x) {
  return fmaxf(x, 0.f) + 0.69314718f * flog2(1.f + fexp2(-1.44269504f * fabsf(x)));
}

// xs[b,k,d,l] = x[b,d,src_index(k,l)]
__device__ __forceinline__ int src_index(int k, int l) {
  int ll = (k & 2) ? (LL - 1 - l) : l;
  int kb = k & 5;
  if (kb == 0) return ll;
  int h = ll & 63, w = ll >> 6;
  if (kb == 1) return (h << 6) + w;
  if (kb == 4) return (h << 6) + ((h + w) & 63);
  return (h << 6) + ((w - h) & 63);
}

__global__ __launch_bounds__(256) void transpose_x(const float* __restrict__ x,
                                                   float* __restrict__ xT) {
  __shared__ float tile[32][33];
  int b  = blockIdx.z;
  int p0 = blockIdx.x * 32;
  int d0 = blockIdx.y * 32;
  int tx = threadIdx.x, ty = threadIdx.y;
  #pragma unroll
  for (int i = 0; i < 32; i += 8)
    tile[ty + i][tx] = x[((size_t)(b * DD + d0 + ty + i)) * LL + p0 + tx];
  __syncthreads();
  #pragma unroll
  for (int i = 0; i < 32; i += 8)
    xT[((size_t)(b * LL + p0 + ty + i)) * DD + d0 + tx] = tile[tx][ty + i];
}

// x_dbl[b,k,l,c] = sum_d xT[b, src_k(l), d] * W[k,c,d];  d split across 2 halves
__global__ __launch_bounds__(256) void proj_kernel(const float* __restrict__ xT,
                                                   const float* __restrict__ W,
                                                   float* __restrict__ xdbl) {
  int k = blockIdx.y, b = blockIdx.z;
  int tx = threadIdx.x;
  int lloc = tx & 127, half = tx >> 7;
  int l = blockIdx.x * 128 + lloc;
  __shared__ __align__(16) float sm[DD * CPAD];  // 30720 B; reused for partials
  for (int i = tx; i < C38 * DD; i += 256) {
    int c = i / DD, dq = i - c * DD;
    sm[dq * CPAD + c] = W[(k * C38 + c) * DD + dq];
  }
  for (int dq = tx; dq < DD; dq += 256) { sm[dq * CPAD + 38] = 0.f; sm[dq * CPAD + 39] = 0.f; }
  __syncthreads();

  int p = src_index(k, l);
  const float4* xrow4 = (const float4*)(xT + ((size_t)b * LL + p) * DD) + half * 24;
  const float* wbase = sm + half * 96 * CPAD;
  float4 acc[10];
  #pragma unroll
  for (int c = 0; c < 10; ++c) acc[c] = make_float4(0.f, 0.f, 0.f, 0.f);

  for (int d4 = 0; d4 < 24; ++d4) {
    float4 xv = xrow4[d4];
    #pragma unroll
    for (int s = 0; s < 4; ++s) {
      float xs = (s == 0) ? xv.x : (s == 1) ? xv.y : (s == 2) ? xv.z : xv.w;
      const float4* w4 = (const float4*)(wbase + (d4 * 4 + s) * CPAD);
      #pragma unroll
      for (int c = 0; c < 10; ++c) {
        float4 wv = w4[c];
        acc[c].x = fmaf(wv.x, xs, acc[c].x);
        acc[c].y = fmaf(wv.y, xs, acc[c].y);
        acc[c].z = fmaf(wv.z, xs, acc[c].z);
        acc[c].w = fmaf(wv.w, xs, acc[c].w);
      }
    }
  }
  __syncthreads();  // Wt no longer needed; reuse sm for partials (128*41 <= 7680)
  if (half == 1) {
    float* pr = sm + lloc * 41;
    const float* af = (const float*)acc;
    #pragma unroll
    for (int c = 0; c < 38; ++c) pr[c] = af[c];
  }
  __syncthreads();
  if (half == 0) {
    const float* pr = sm + lloc * 41;
    float* af = (float*)acc;
    #pragma unroll
    for (int c = 0; c < 38; ++c) af[c] += pr[c];
    float* orow = xdbl + ((size_t)((b * KK + k) * LL) + l) * CPAD;
    float4* o4 = (float4*)orow;
    #pragma unroll
    for (int c = 0; c < 9; ++c) o4[c] = acc[c];
    orow[36] = acc[9].x;
    orow[37] = acc[9].y;
  }
}

// Scan: wave = 32 d x 2 n-halves; block (64,6) covers 192 d of ONE chunk (L1 row sharing).
// Phase A (FINAL=false): S = sum softplus, q = local final h (h0=0).
// Phase C (FINAL=true):  recurrence from stitched h0; fused cross_merge scatter-add.
template <bool FINAL>
__global__ __launch_bounds__(384, 5) void scan_kernel(
    const float* __restrict__ xT, const float* __restrict__ xdbl,
    const float* __restrict__ A_logs, const float* __restrict__ dtw,
    const float* __restrict__ dtb, const float* __restrict__ Ds,
    float* __restrict__ Pq, float* __restrict__ Y) {
  const int lane = threadIdx.x;        // 0..63
  const int ng   = lane >> 5;          // n-half
  const int dd   = threadIdx.y;        // 0..5
  const int bk   = blockIdx.x;         // 0..15
  const int chunk = blockIdx.y;        // 0..NCH-1
  const int b = bk >> 3, k = bk & 7;
  const int d  = dd * 32 + (lane & 31);
  const int kd = k * DD + d;
  const int ch = bk * DD + d;

  float An2[8];
  {
    const float* ap = A_logs + (size_t)kd * NN + ng * 8;
    #pragma unroll
    for (int j = 0; j < 8; ++j) An2[j] = -__expf(ap[j]) * 1.44269504f;
  }
  float wdt[RR];
  #pragma unroll
  for (int r = 0; r < RR; ++r) wdt[r] = dtw[kd * RR + r];
  const float bias = dtb[kd];
  const float dval = FINAL ? Ds[kd] : 0.f;

  float h[8];
  if constexpr (FINAL) {
    const float* h0p = Pq + ((size_t)ch * NCH + chunk) * PQS + 1 + ng * 8;
    #pragma unroll
    for (int j = 0; j < 8; ++j) h[j] = h0p[j];
  } else {
    #pragma unroll
    for (int j = 0; j < 8; ++j) h[j] = 0.f;
  }

  const int l0 = chunk * CLEN;
  const float* rowbase = xdbl + ((size_t)(bk * LL) + l0) * CPAD;
  const float* xTb = xT + (size_t)b * LL * DD + d;

  float S = 0.f;
  float sp[2], uu[2], Bv[2][8], Cv[2][8];
  int   pp[2];

  auto LOADT = [&](int t, int s) {
    const float* row = rowbase + (size_t)t * CPAD;
    const float2* r2 = (const float2*)row;
    float2 d01 = r2[0], d23 = r2[1], d45 = r2[2];
    float dts = bias;
    dts = fmaf(d01.x, wdt[0], dts);
    dts = fmaf(d01.y, wdt[1], dts);
    dts = fmaf(d23.x, wdt[2], dts);
    dts = fmaf(d23.y, wdt[3], dts);
    dts = fmaf(d45.x, wdt[4], dts);
    dts = fmaf(d45.y, wdt[5], dts);
    sp[s] = softplus_f(dts);
    const float2* bq = (const float2*)(row + 6 + ng * 8);
    #pragma unroll
    for (int j = 0; j < 4; ++j) {
      float2 v = bq[j];
      Bv[s][2 * j] = v.x; Bv[s][2 * j + 1] = v.y;
    }
    if constexpr (FINAL) {
      const float2* cq = (const float2*)(row + 22 + ng * 8);
      #pragma unroll
      for (int j = 0; j < 4; ++j) {
        float2 v = cq[j];
        Cv[s][2 * j] = v.x; Cv[s][2 * j + 1] = v.y;
      }
    }
    int p = src_index(k, l0 + t);
    pp[s] = p;
    uu[s] = xTb[(size_t)p * DD];
  };

  auto COMPUTE = [&](int s) {
    float spv = sp[s];
    float du = spv * uu[s];
    #pragma unroll
    for (int j = 0; j < 8; ++j) {
      float e = fexp2(spv * An2[j]);
      h[j] = fmaf(h[j], e, du * Bv[s][j]);
    }
    if constexpr (FINAL) {
      float y = 0.f;
      #pragma unroll
      for (int j = 0; j < 8; ++j) y = fmaf(h[j], Cv[s][j], y);
      y += __shfl_xor(y, 32, 64);
      if (ng == 0) {
        float outv = fmaf(uu[s], dval, y);
        atomicAdd(&Y[(size_t)(b * LL + pp[s]) * DD + d], outv);
      }
    } else {
      S += spv;
    }
  };

  LOADT(0, 0);
  for (int t = 0; t < CLEN; t += 2) {
    LOADT(t + 1, 1);
    COMPUTE(0);
    int t2 = (t + 2 < CLEN) ? t + 2 : CLEN - 1;
    LOADT(t2, 0);
    COMPUTE(1);
  }

  if constexpr (!FINAL) {
    float* rec = Pq + ((size_t)ch * NCH + chunk) * PQS;
    if (ng == 0) rec[0] = S;
    float* qp = rec + 1 + ng * 8;
    #pragma unroll
    for (int j = 0; j < 8; ++j) qp[j] = h[j];
  }
}

// Wave-parallel stitch: one wave per (ch, n); shuffle scan of (P,q) composition.
__global__ __launch_bounds__(256) void stitch_kernel(float* __restrict__ Pq,
                                                     const float* __restrict__ A_logs) {
  int lane = threadIdx.x & 63;
  int gw = (blockIdx.x * 256 + threadIdx.x) >> 6;  // 0..49151
  int ch = gw >> 4, n = gw & 15;
  int kd = ch % (KK * DD);
  float An2 = -__expf(A_logs[(size_t)kd * NN + n]) * 1.44269504f;

  float* rec = Pq + ((size_t)ch * NCH + lane) * PQS;
  float P = fexp2(An2 * rec[0]);
  float q = rec[1 + n];

  float Pt = P, qt = q;
  #pragma unroll
  for (int off = 1; off < 64; off <<= 1) {
    float Pp = __shfl_up(Pt, off, 64);
    float qp = __shfl_up(qt, off, 64);
    if (lane >= off) { qt = fmaf(Pt, qp, qt); Pt *= Pp; }
  }
  float hx = __shfl_up(qt, 1, 64);
  if (lane == 0) hx = 0.f;
  rec[1 + n] = hx;  // h0 for this chunk
}

__global__ __launch_bounds__(256) void ln_kernel(const float* __restrict__ Y,
                                                 const float* __restrict__ lw,
                                                 const float* __restrict__ lb,
                                                 float* __restrict__ out) {
  int lane = threadIdx.x & 63;
  int row = blockIdx.x * 4 + (threadIdx.x >> 6);
  const float* yr = Y + (size_t)row * DD;
  float v0 = yr[lane], v1 = yr[lane + 64], v2 = yr[lane + 128];
  float s1 = v0 + v1 + v2;
  float s2 = v0 * v0 + v1 * v1 + v2 * v2;
  #pragma unroll
  for (int m = 32; m >= 1; m >>= 1) {
    s1 += __shfl_xor(s1, m, 64);
    s2 += __shfl_xor(s2, m, 64);
  }
  float mu = s1 * (1.f / DD);
  float var = s2 * (1.f / DD) - mu * mu;
  float inv = rsqrtf(var + 1e-5f);
  float* orow = out + (size_t)row * DD;
  orow[lane]       = (v0 - mu) * inv * lw[lane]       + lb[lane];
  orow[lane + 64]  = (v1 - mu) * inv * lw[lane + 64]  + lb[lane + 64];
  orow[lane + 128] = (v2 - mu) * inv * lw[lane + 128] + lb[lane + 128];
}

extern "C" void kernel_launch(void* const* d_in, const int* in_sizes, int n_in,
                              void* d_out, int out_size, void* d_ws, size_t ws_size,
                              hipStream_t stream) {
  const float* x      = (const float*)d_in[0];
  const float* xpw    = (const float*)d_in[1];
  const float* dtw    = (const float*)d_in[2];
  const float* dtb    = (const float*)d_in[3];
  const float* A_logs = (const float*)d_in[4];
  const float* Ds     = (const float*)d_in[5];
  const float* ln_w   = (const float*)d_in[6];
  const float* ln_b   = (const float*)d_in[7];
  float* out = (float*)d_out;

  float* ws   = (float*)d_ws;
  float* xT   = ws;                    // B*L*D       = 1572864 floats
  float* xdbl = xT + 1572864;          // B*K*L*CPAD  = 2621440
  float* Y    = xdbl + 2621440;        // B*L*D       = 1572864
  float* Pq   = Y + 1572864;           // 3072*64*17  = 3342336

  hipMemsetAsync(Y, 0, 1572864 * sizeof(float), stream);
  transpose_x<<<dim3(LL / 32, DD / 32, BB), dim3(32, 8), 0, stream>>>(x, xT);
  proj_kernel<<<dim3(LL / 128, KK, BB), 256, 0, stream>>>(xT, xpw, xdbl);
  scan_kernel<false><<<dim3(BB * KK, NCH), dim3(64, 6), 0, stream>>>(
      xT, xdbl, A_logs, dtw, dtb, Ds, Pq, Y);
  stitch_kernel<<<(3072 * 16 * 64) / 256, 256, 0, stream>>>(Pq, A_logs);
  scan_kernel<true><<<dim3(BB * KK, NCH), dim3(64, 6), 0, stream>>>(
      xT, xdbl, A_logs, dtw, dtb, Ds, Pq, Y);
  ln_kernel<<<(BB * LL) / 4, 256, 0, stream>>>(Y, ln_w, ln_b, out);
}